// Round 4
// baseline (293.931 us; speedup 1.0000x reference)
//
#include <hip/hip_runtime.h>
#include <stdint.h>

// Problem constants
#define B_   16
#define D_   256
#define T_   4096
#define K_   1024
#define N_   (B_ * T_)      // 65536 points
#define BM   64             // points per block

typedef __attribute__((ext_vector_type(4))) float floatx4;
typedef __attribute__((ext_vector_type(2))) float floatx2;
typedef __attribute__((ext_vector_type(2))) long longx2;

// ---- Kernel 0: emb fp32 -> fp8 e4m3 (scaled x1024), stored in PIECE order:
// tile ct = codes [ct*16, ct*16+16), 4 KB = 4 pieces of 1 KB. Byte for
// (code c, dim d): ct=c>>4, ml=c&15, kk=d>>5, quad=(d>>3)&3, b=d&7 at
//   ct*4096 + (kk>>1)*1024 + (quad*16+ml)*16 + (kk&1)*8 + b
// -> k-loop lane L=(quad*16+ml) reads piece i at ct*4096+i*1024+L*16: each
// load instruction covers 1 KB CONTIGUOUS across the wave (R2's coalescing)
// and lands directly in B-fragment registers (R3's barrier-free k-loop).
// esqh[c] = 1024 * 0.5 * ||e_exact||^2 (pre-quantization). Also zeroes loss.
__global__ __launch_bounds__(256) void emb_prep(const float* __restrict__ emb,
                                                uint32_t* __restrict__ embf8,
                                                float* __restrict__ esqh,
                                                float* __restrict__ lossp) {
    int w = threadIdx.x >> 6, lane = threadIdx.x & 63;
    int k = blockIdx.x * 4 + w;                       // one wave per code row
    float4 v = ((const float4*)emb)[k * 64 + lane];   // d0 = lane*4
    float a0 = v.x * 1024.f, a1 = v.y * 1024.f, a2 = v.z * 1024.f, a3 = v.w * 1024.f;
    int p = __builtin_amdgcn_cvt_pk_fp8_f32(a0, a1, 0, false);
    p = __builtin_amdgcn_cvt_pk_fp8_f32(a2, a3, p, true);
    int kk = lane >> 3, quad = (lane >> 1) & 3;       // from d0 = lane*4
    int widx = (k >> 4) * 1024 + (kk >> 1) * 256 + (quad * 16 + (k & 15)) * 4
             + (kk & 1) * 2 + (lane & 1);
    embf8[widx] = (uint32_t)p;
    float ss = a0 * a0 + a1 * a1 + a2 * a2 + a3 * a3;   // exact (pre-fp8) scaled norm
    #pragma unroll
    for (int off = 32; off; off >>= 1) ss += __shfl_xor(ss, off, 64);
    if (lane == 0) esqh[k] = ss * (0.5f / 1024.f);      // = 1024 * 0.5*||e||^2
    if (blockIdx.x == 0 && threadIdx.x == 0) *lossp = 0.f;
}

// ---- Main kernel ----
// xs swizzle (phases 1-3), byte offset of d in row t:
//   c=d>>4, h=(d>>3)&1 -> ((c ^ (t&15))<<4) + ((h ^ ((t>>4)&1))<<3) + (d&7)
// Phase 4 reuses xs with a 16B-chunk swizzle: chunk g at ((g ^ (t&15))<<4).
// Work split: wave w owns ALL 64 points (4 A-sets, 32 MFMA/tile) x code
// quarter [w*16, w*16+16) tiles. Zero barriers in the k-loop; depth-2 tile
// register pipeline covers L2 latency. launch_bounds(256,2): grid 1024 runs
// as exactly 2 even passes of 2 blocks/CU (no ragged tail at 3/CU).
__global__ __launch_bounds__(256, 2) void vq_main(const float* __restrict__ z,
                                                  const uint32_t* __restrict__ embf8,
                                                  const float* __restrict__ esqh,
                                                  float* __restrict__ out0,
                                                  float* __restrict__ lossp) {
    __shared__ __align__(16) unsigned char xs[BM * 256];   // 16 KiB
    __shared__ float wvals[4][BM];
    __shared__ int   widxs[4][BM];
    __shared__ int   pidx[BM];
    __shared__ float zred[4];

    int tid  = threadIdx.x;
    int lane = tid & 63, w = tid >> 6;
    int ml   = lane & 15, quad = lane >> 4;
    int blk  = blockIdx.x;
    int b    = blk >> 6;
    int t0   = (blk & 63) * BM;
    const float* zb = z + (size_t)b * (D_ * T_) + t0;

    // ---- Phase 1: load z [d][t], fp8-convert, transposed+swizzled store; Sum z^2 ----
    float zsq = 0.f;
    {
        int t = lane, hf = (t >> 4) & 1;
        #pragma unroll 2
        for (int j = 0; j < 8; ++j) {
            int dgrp = w + 4 * j;
            int d0 = dgrp * 8;
            float f0 = zb[(d0 + 0) * T_ + t];
            float f1 = zb[(d0 + 1) * T_ + t];
            float f2 = zb[(d0 + 2) * T_ + t];
            float f3 = zb[(d0 + 3) * T_ + t];
            float f4 = zb[(d0 + 4) * T_ + t];
            float f5 = zb[(d0 + 5) * T_ + t];
            float f6 = zb[(d0 + 6) * T_ + t];
            float f7 = zb[(d0 + 7) * T_ + t];
            zsq += f0*f0 + f1*f1 + f2*f2 + f3*f3 + f4*f4 + f5*f5 + f6*f6 + f7*f7;
            uint32_t p0 = (uint32_t)__builtin_amdgcn_cvt_pk_fp8_f32(f0, f1, 0, false);
            p0 = (uint32_t)__builtin_amdgcn_cvt_pk_fp8_f32(f2, f3, (int)p0, true);
            uint32_t p1 = (uint32_t)__builtin_amdgcn_cvt_pk_fp8_f32(f4, f5, 0, false);
            p1 = (uint32_t)__builtin_amdgcn_cvt_pk_fp8_f32(f6, f7, (int)p1, true);
            int c = dgrp >> 1, h = dgrp & 1;
            *(uint2*)&xs[t * 256 + ((c ^ (t & 15)) << 4) + ((h ^ hf) << 3)] =
                make_uint2(p0, p1);
        }
    }
    __syncthreads();

    // ---- Phase 2: persistent A fragments, ALL 4 point-sets per wave ----
    long afr[4][8];
    #pragma unroll
    for (int s = 0; s < 4; ++s) {
        int pnt = s * 16 + ml;
        #pragma unroll
        for (int kk = 0; kk < 8; ++kk) {
            int c = 2 * kk + (quad >> 1), h = quad & 1;
            afr[s][kk] = *(const long*)&xs[pnt * 256 + ((c ^ ml) << 4) + ((h ^ (s & 1)) << 3)];
        }
    }

    float bv[4][4]; int bi[4][4];
    #pragma unroll
    for (int s = 0; s < 4; ++s)
        #pragma unroll
        for (int i = 0; i < 4; ++i) { bv[s][i] = 1e30f; bi[s][i] = 0; }

    // ---- Phase 3: barrier-free k-loop, coalesced piece loads, depth-2 pipeline ----
    const char* ebL = (const char*)embf8 + (size_t)lane * 16;
    int ct0 = w * 16;
    longx2 q[3][4]; float eh[3];
    #pragma unroll
    for (int pl = 0; pl < 2; ++pl) {
        size_t base = (size_t)(ct0 + pl) * 4096;
        #pragma unroll
        for (int i = 0; i < 4; ++i)
            q[pl][i] = *(const longx2*)(ebL + base + i * 1024);
        eh[pl] = esqh[(ct0 + pl) * 16 + ml];
    }
    #pragma unroll
    for (int j = 0; j < 16; ++j) {
        int cur = j % 3, nxt = (j + 2) % 3;
        if (j + 2 < 16) {
            size_t base = (size_t)(ct0 + j + 2) * 4096;
            #pragma unroll
            for (int i = 0; i < 4; ++i)
                q[nxt][i] = *(const longx2*)(ebL + base + i * 1024);
            eh[nxt] = esqh[(ct0 + j + 2) * 16 + ml];
        }
        floatx4 a0 = {0,0,0,0}, a1 = {0,0,0,0}, a2 = {0,0,0,0}, a3 = {0,0,0,0};
        #pragma unroll
        for (int i = 0; i < 4; ++i) {
            long bf0 = q[cur][i][0], bf1 = q[cur][i][1];   // frags kk=2i, 2i+1
            a0 = __builtin_amdgcn_mfma_f32_16x16x32_fp8_fp8(afr[0][2*i],     bf0, a0, 0, 0, 0);
            a1 = __builtin_amdgcn_mfma_f32_16x16x32_fp8_fp8(afr[1][2*i],     bf0, a1, 0, 0, 0);
            a2 = __builtin_amdgcn_mfma_f32_16x16x32_fp8_fp8(afr[2][2*i],     bf0, a2, 0, 0, 0);
            a3 = __builtin_amdgcn_mfma_f32_16x16x32_fp8_fp8(afr[3][2*i],     bf0, a3, 0, 0, 0);
            a0 = __builtin_amdgcn_mfma_f32_16x16x32_fp8_fp8(afr[0][2*i + 1], bf1, a0, 0, 0, 0);
            a1 = __builtin_amdgcn_mfma_f32_16x16x32_fp8_fp8(afr[1][2*i + 1], bf1, a1, 0, 0, 0);
            a2 = __builtin_amdgcn_mfma_f32_16x16x32_fp8_fp8(afr[2][2*i + 1], bf1, a2, 0, 0, 0);
            a3 = __builtin_amdgcn_mfma_f32_16x16x32_fp8_fp8(afr[3][2*i + 1], bf1, a3, 0, 0, 0);
        }
        // scaled dist = 1024*(0.5||e||^2 - x.e); C layout: code=lane&15, row=quad*4+i
        int c = (ct0 + j) * 16 + ml;
        float ehc = eh[cur];
        #pragma unroll
        for (int i = 0; i < 4; ++i) {
            float v0 = ehc - a0[i]; if (v0 < bv[0][i]) { bv[0][i] = v0; bi[0][i] = c; }
            float v1 = ehc - a1[i]; if (v1 < bv[1][i]) { bv[1][i] = v1; bi[1][i] = c; }
            float v2 = ehc - a2[i]; if (v2 < bv[2][i]) { bv[2][i] = v2; bi[2][i] = c; }
            float v3 = ehc - a3[i]; if (v3 < bv[3][i]) { bv[3][i] = v3; bi[3][i] = c; }
        }
    }

    // ---- per-wave argmin over the 16 code-lanes; publish candidates ----
    #pragma unroll
    for (int s = 0; s < 4; ++s)
        #pragma unroll
        for (int i = 0; i < 4; ++i) {
            float v = bv[s][i]; int ii = bi[s][i];
            #pragma unroll
            for (int off = 1; off < 16; off <<= 1) {
                float ov = __shfl_xor(v, off, 64);
                int   oi = __shfl_xor(ii, off, 64);
                if (ov < v || (ov == v && oi < ii)) { v = ov; ii = oi; }
            }
            if (ml == 0) {
                int pnt = s * 16 + quad * 4 + i;
                wvals[w][pnt] = v; widxs[w][pnt] = ii;
            }
        }
    #pragma unroll
    for (int off = 32; off; off >>= 1) zsq += __shfl_xor(zsq, off, 64);
    if (lane == 0) zred[w] = zsq;
    __syncthreads();

    // ---- cross-wave merge (wave 0) + loss via algebra ----
    if (tid < 64) {
        int t = tid;
        float wv = wvals[0][t]; int wi = widxs[0][t];
        #pragma unroll
        for (int ww = 1; ww < 4; ++ww) {
            float v = wvals[ww][t]; int ii = widxs[ww][t];
            if (v < wv || (v == wv && ii < wi)) { wv = v; wi = ii; }
        }
        pidx[t] = wi;
        float lsum = wv;          // winning bv = 1024*(0.5||e||^2 - x.e)
        #pragma unroll
        for (int off = 32; off; off >>= 1) lsum += __shfl_xor(lsum, off, 64);
        if (t == 0) {
            float tot = zred[0] + zred[1] + zred[2] + zred[3] + lsum * (2.0f / 1024.f);
            atomicAdd(lossp, tot * (1.25f / 16777216.0f));   // 1.25/(N*D)
        }
    }
    __syncthreads();

    // ---- Phase 4a: gather winning fp8 rows into xs (piece layout) ----
    #pragma unroll
    for (int m = 0; m < 4; ++m) {
        int t = (tid >> 4) + 16 * m;
        int g = tid & 15;             // chunk: piece i=g>>2, q=g&3
        int code = pidx[t];
        const char* src = (const char*)embf8 + (size_t)(code >> 4) * 4096
                        + (g >> 2) * 1024 + ((g & 3) * 16 + (code & 15)) * 16;
        uint4 v = *(const uint4*)src;
        *(uint4*)&xs[t * 256 + ((g ^ (t & 15)) << 4)] = v;
    }
    __syncthreads();

    // ---- Phase 4b: dequant + transpose-write (piece-order byte decode) ----
    float* ob = out0 + (size_t)b * (D_ * T_) + t0;
    {
        int t = lane;
        #pragma unroll
        for (int jj = 0; jj < 4; ++jj) {
            int g = w + 4 * jj;            // 16-byte chunk 0..15
            uint4 v = *(const uint4*)&xs[t * 256 + ((g ^ (t & 15)) << 4)];
            uint32_t wd[4] = {v.x, v.y, v.z, v.w};
            #pragma unroll
            for (int u = 0; u < 4; ++u) {
                int kk = (g >> 2) * 2 + (u >> 1);
                int d0 = kk * 32 + (g & 3) * 8 + (u & 1) * 4;
                floatx2 lo = __builtin_amdgcn_cvt_pk_f32_fp8((int)wd[u], false);
                floatx2 hi = __builtin_amdgcn_cvt_pk_f32_fp8((int)wd[u], true);
                ob[(d0 + 0) * T_ + t] = lo[0] * (1.f / 1024.f);
                ob[(d0 + 1) * T_ + t] = lo[1] * (1.f / 1024.f);
                ob[(d0 + 2) * T_ + t] = hi[0] * (1.f / 1024.f);
                ob[(d0 + 3) * T_ + t] = hi[1] * (1.f / 1024.f);
            }
        }
    }
}

extern "C" void kernel_launch(void* const* d_in, const int* in_sizes, int n_in,
                              void* d_out, int out_size, void* d_ws, size_t ws_size,
                              hipStream_t stream) {
    (void)in_sizes; (void)n_in; (void)out_size; (void)ws_size;
    const float* z   = (const float*)d_in[0];
    const float* emb = (const float*)d_in[1];

    uint32_t* embf8 = (uint32_t*)d_ws;                              // 256 KiB
    float*    esqh  = (float*)((char*)d_ws + (size_t)K_ * D_);      // 4 KiB

    float* out0  = (float*)d_out;
    float* lossp = out0 + (size_t)N_ * D_;

    emb_prep<<<K_ / 4, 256, 0, stream>>>(emb, embf8, esqh, lossp);
    vq_main<<<N_ / BM, 256, 0, stream>>>(z, embf8, esqh, out0, lossp);
}

// Round 5
// 143.642 us; speedup vs baseline: 2.0463x; 2.0463x over previous
//
#include <hip/hip_runtime.h>
#include <stdint.h>

// Problem constants
#define B_   16
#define D_   256
#define T_   4096
#define K_   1024
#define N_   (B_ * T_)      // 65536 points
#define BM   64             // points per block

typedef __attribute__((ext_vector_type(4))) float floatx4;
typedef __attribute__((ext_vector_type(2))) float floatx2;
typedef __attribute__((ext_vector_type(2))) long longx2;

// ---- Kernel 0: emb fp32 -> fp8 e4m3 (scaled x1024), stored in PIECE order:
// tile ct = codes [ct*16, ct*16+16), 4 KB = 4 pieces of 1 KB. Byte for
// (code c, dim d): ct=c>>4, ml=c&15, kk=d>>5, quad=(d>>3)&3, b=d&7 at
//   ct*4096 + (kk>>1)*1024 + (quad*16+ml)*16 + (kk&1)*8 + b
// -> k-loop lane L=(quad*16+ml) reads piece i at ct*4096+i*1024+L*16: each
// load covers 1 KB contiguous across the wave and lands directly in MFMA
// B-fragment registers. esqh[c] = 1024*0.5*||e_exact||^2. Also zeroes loss.
__global__ __launch_bounds__(256) void emb_prep(const float* __restrict__ emb,
                                                uint32_t* __restrict__ embf8,
                                                float* __restrict__ esqh,
                                                float* __restrict__ lossp) {
    int w = threadIdx.x >> 6, lane = threadIdx.x & 63;
    int k = blockIdx.x * 4 + w;                       // one wave per code row
    float4 v = ((const float4*)emb)[k * 64 + lane];   // d0 = lane*4
    float a0 = v.x * 1024.f, a1 = v.y * 1024.f, a2 = v.z * 1024.f, a3 = v.w * 1024.f;
    int p = __builtin_amdgcn_cvt_pk_fp8_f32(a0, a1, 0, false);
    p = __builtin_amdgcn_cvt_pk_fp8_f32(a2, a3, p, true);
    int kk = lane >> 3, quad = (lane >> 1) & 3;       // from d0 = lane*4
    int widx = (k >> 4) * 1024 + (kk >> 1) * 256 + (quad * 16 + (k & 15)) * 4
             + (kk & 1) * 2 + (lane & 1);
    embf8[widx] = (uint32_t)p;
    float ss = a0 * a0 + a1 * a1 + a2 * a2 + a3 * a3;   // exact (pre-fp8) scaled norm
    #pragma unroll
    for (int off = 32; off; off >>= 1) ss += __shfl_xor(ss, off, 64);
    if (lane == 0) esqh[k] = ss * (0.5f / 1024.f);      // = 1024 * 0.5*||e||^2
    if (blockIdx.x == 0 && threadIdx.x == 0) *lossp = 0.f;
}

// ---- Main kernel ----
// xs swizzle (phases 1-3), byte offset of d in row t:
//   c=d>>4, h=(d>>3)&1 -> ((c ^ (t&15))<<4) + ((h ^ ((t>>4)&1))<<3) + (d&7)
// Phase 4 reuses xs with a 16B-chunk swizzle: chunk g at ((g ^ (t&15))<<4).
// Wave w owns ALL 64 points (4 A-sets, 32 MFMA/tile) x code quarter
// [w*16, w*16+16) tiles. Zero barriers in the k-loop.
// Argmin state is ONE packed float per acc element: low 10 mantissa bits
// replaced by the code index (K=1024); v_min_f32 compares true value to
// 2^-13 relative, index rides along. Ties -> allowed argmin flips.
// Register budget (the R4 lesson): afr 64 + tile loads 16x2 + acc 16 +
// bv 16 + misc ~12 ~= 140. launch_bounds(256,3) caps at ~170: NO spill.
__global__ __launch_bounds__(256, 3) void vq_main(const float* __restrict__ z,
                                                  const uint32_t* __restrict__ embf8,
                                                  const float* __restrict__ esqh,
                                                  float* __restrict__ out0,
                                                  float* __restrict__ lossp) {
    __shared__ __align__(16) unsigned char xs[BM * 256];   // 16 KiB
    __shared__ float wvals[4][BM];
    __shared__ int   pidx[BM];
    __shared__ float zred[4];

    int tid  = threadIdx.x;
    int lane = tid & 63, w = tid >> 6;
    int ml   = lane & 15, quad = lane >> 4;
    int blk  = blockIdx.x;
    int b    = blk >> 6;
    int t0   = (blk & 63) * BM;
    const float* zb = z + (size_t)b * (D_ * T_) + t0;

    // ---- Phase 1: load z [d][t], fp8-convert, transposed+swizzled store; Sum z^2 ----
    float zsq = 0.f;
    {
        int t = lane, hf = (t >> 4) & 1;
        #pragma unroll 2
        for (int j = 0; j < 8; ++j) {
            int dgrp = w + 4 * j;
            int d0 = dgrp * 8;
            float f0 = zb[(d0 + 0) * T_ + t];
            float f1 = zb[(d0 + 1) * T_ + t];
            float f2 = zb[(d0 + 2) * T_ + t];
            float f3 = zb[(d0 + 3) * T_ + t];
            float f4 = zb[(d0 + 4) * T_ + t];
            float f5 = zb[(d0 + 5) * T_ + t];
            float f6 = zb[(d0 + 6) * T_ + t];
            float f7 = zb[(d0 + 7) * T_ + t];
            zsq += f0*f0 + f1*f1 + f2*f2 + f3*f3 + f4*f4 + f5*f5 + f6*f6 + f7*f7;
            uint32_t p0 = (uint32_t)__builtin_amdgcn_cvt_pk_fp8_f32(f0, f1, 0, false);
            p0 = (uint32_t)__builtin_amdgcn_cvt_pk_fp8_f32(f2, f3, (int)p0, true);
            uint32_t p1 = (uint32_t)__builtin_amdgcn_cvt_pk_fp8_f32(f4, f5, 0, false);
            p1 = (uint32_t)__builtin_amdgcn_cvt_pk_fp8_f32(f6, f7, (int)p1, true);
            int c = dgrp >> 1, h = dgrp & 1;
            *(uint2*)&xs[t * 256 + ((c ^ (t & 15)) << 4) + ((h ^ hf) << 3)] =
                make_uint2(p0, p1);
        }
    }
    __syncthreads();

    // ---- Phase 2: persistent A fragments, ALL 4 point-sets per wave ----
    long afr[4][8];
    #pragma unroll
    for (int s = 0; s < 4; ++s) {
        int pnt = s * 16 + ml;
        #pragma unroll
        for (int kk = 0; kk < 8; ++kk) {
            int c = 2 * kk + (quad >> 1), h = quad & 1;
            afr[s][kk] = *(const long*)&xs[pnt * 256 + ((c ^ ml) << 4) + ((h ^ (s & 1)) << 3)];
        }
    }

    float bv[4][4];
    #pragma unroll
    for (int s = 0; s < 4; ++s)
        #pragma unroll
        for (int i = 0; i < 4; ++i) bv[s][i] = 1e30f;

    // ---- Phase 3: barrier-free k-loop, coalesced piece loads -> B-frags ----
    int ct0 = w * 16;
    const char* ebL = (const char*)embf8 + (size_t)ct0 * 4096 + (size_t)lane * 16;
    const unsigned hi_mask = 0xFFFFFC00u;
    #pragma unroll 2
    for (int j = 0; j < 16; ++j) {
        const char* p = ebL + (size_t)j * 4096;
        longx2 qq[4];
        #pragma unroll
        for (int i = 0; i < 4; ++i)
            qq[i] = *(const longx2*)(p + i * 1024);
        float eh = esqh[(ct0 + j) * 16 + ml];
        floatx4 a0 = {0,0,0,0}, a1 = {0,0,0,0}, a2 = {0,0,0,0}, a3 = {0,0,0,0};
        #pragma unroll
        for (int i = 0; i < 4; ++i) {
            long bf0 = qq[i][0], bf1 = qq[i][1];   // frags kk=2i, 2i+1
            a0 = __builtin_amdgcn_mfma_f32_16x16x32_fp8_fp8(afr[0][2*i],     bf0, a0, 0, 0, 0);
            a1 = __builtin_amdgcn_mfma_f32_16x16x32_fp8_fp8(afr[1][2*i],     bf0, a1, 0, 0, 0);
            a2 = __builtin_amdgcn_mfma_f32_16x16x32_fp8_fp8(afr[2][2*i],     bf0, a2, 0, 0, 0);
            a3 = __builtin_amdgcn_mfma_f32_16x16x32_fp8_fp8(afr[3][2*i],     bf0, a3, 0, 0, 0);
            a0 = __builtin_amdgcn_mfma_f32_16x16x32_fp8_fp8(afr[0][2*i + 1], bf1, a0, 0, 0, 0);
            a1 = __builtin_amdgcn_mfma_f32_16x16x32_fp8_fp8(afr[1][2*i + 1], bf1, a1, 0, 0, 0);
            a2 = __builtin_amdgcn_mfma_f32_16x16x32_fp8_fp8(afr[2][2*i + 1], bf1, a2, 0, 0, 0);
            a3 = __builtin_amdgcn_mfma_f32_16x16x32_fp8_fp8(afr[3][2*i + 1], bf1, a3, 0, 0, 0);
        }
        // packed key = bits(1024*(0.5||e||^2 - x.e)) with low 10 bits = code
        unsigned cbits = (unsigned)((ct0 + j) * 16 + ml);
        #pragma unroll
        for (int i = 0; i < 4; ++i) {
            float d0 = eh - a0[i];
            bv[0][i] = fminf(bv[0][i], __uint_as_float((__float_as_uint(d0) & hi_mask) | cbits));
            float d1 = eh - a1[i];
            bv[1][i] = fminf(bv[1][i], __uint_as_float((__float_as_uint(d1) & hi_mask) | cbits));
            float d2 = eh - a2[i];
            bv[2][i] = fminf(bv[2][i], __uint_as_float((__float_as_uint(d2) & hi_mask) | cbits));
            float d3 = eh - a3[i];
            bv[3][i] = fminf(bv[3][i], __uint_as_float((__float_as_uint(d3) & hi_mask) | cbits));
        }
    }

    // ---- per-wave min over the 16 code-lanes; publish packed candidates ----
    #pragma unroll
    for (int s = 0; s < 4; ++s)
        #pragma unroll
        for (int i = 0; i < 4; ++i) {
            float v = bv[s][i];
            #pragma unroll
            for (int off = 1; off < 16; off <<= 1)
                v = fminf(v, __shfl_xor(v, off, 64));
            if (ml == 0) wvals[w][s * 16 + quad * 4 + i] = v;
        }
    #pragma unroll
    for (int off = 32; off; off >>= 1) zsq += __shfl_xor(zsq, off, 64);
    if (lane == 0) zred[w] = zsq;
    __syncthreads();

    // ---- cross-wave merge (wave 0) + loss via algebra ----
    if (tid < 64) {
        int t = tid;
        float wv = fminf(fminf(wvals[0][t], wvals[1][t]),
                         fminf(wvals[2][t], wvals[3][t]));
        pidx[t] = (int)(__float_as_uint(wv) & 1023u);
        float lsum = wv;          // packed float == bv to 2^-13 relative
        #pragma unroll
        for (int off = 32; off; off >>= 1) lsum += __shfl_xor(lsum, off, 64);
        if (t == 0) {
            float tot = zred[0] + zred[1] + zred[2] + zred[3] + lsum * (2.0f / 1024.f);
            atomicAdd(lossp, tot * (1.25f / 16777216.0f));   // 1.25/(N*D)
        }
    }
    __syncthreads();

    // ---- Phase 4a: gather winning fp8 rows into xs (piece layout) ----
    #pragma unroll
    for (int m = 0; m < 4; ++m) {
        int t = (tid >> 4) + 16 * m;
        int g = tid & 15;             // chunk: piece i=g>>2, q=g&3
        int code = pidx[t];
        const char* src = (const char*)embf8 + (size_t)(code >> 4) * 4096
                        + (g >> 2) * 1024 + ((g & 3) * 16 + (code & 15)) * 16;
        uint4 v = *(const uint4*)src;
        *(uint4*)&xs[t * 256 + ((g ^ (t & 15)) << 4)] = v;
    }
    __syncthreads();

    // ---- Phase 4b: dequant + transpose-write (piece-order byte decode) ----
    float* ob = out0 + (size_t)b * (D_ * T_) + t0;
    {
        int t = lane;
        #pragma unroll
        for (int jj = 0; jj < 4; ++jj) {
            int g = w + 4 * jj;            // 16-byte chunk 0..15
            uint4 v = *(const uint4*)&xs[t * 256 + ((g ^ (t & 15)) << 4)];
            uint32_t wd[4] = {v.x, v.y, v.z, v.w};
            #pragma unroll
            for (int u = 0; u < 4; ++u) {
                int kk = (g >> 2) * 2 + (u >> 1);
                int d0 = kk * 32 + (g & 3) * 8 + (u & 1) * 4;
                floatx2 lo = __builtin_amdgcn_cvt_pk_f32_fp8((int)wd[u], false);
                floatx2 hi = __builtin_amdgcn_cvt_pk_f32_fp8((int)wd[u], true);
                ob[(d0 + 0) * T_ + t] = lo[0] * (1.f / 1024.f);
                ob[(d0 + 1) * T_ + t] = lo[1] * (1.f / 1024.f);
                ob[(d0 + 2) * T_ + t] = hi[0] * (1.f / 1024.f);
                ob[(d0 + 3) * T_ + t] = hi[1] * (1.f / 1024.f);
            }
        }
    }
}

extern "C" void kernel_launch(void* const* d_in, const int* in_sizes, int n_in,
                              void* d_out, int out_size, void* d_ws, size_t ws_size,
                              hipStream_t stream) {
    (void)in_sizes; (void)n_in; (void)out_size; (void)ws_size;
    const float* z   = (const float*)d_in[0];
    const float* emb = (const float*)d_in[1];

    uint32_t* embf8 = (uint32_t*)d_ws;                              // 256 KiB
    float*    esqh  = (float*)((char*)d_ws + (size_t)K_ * D_);      // 4 KiB

    float* out0  = (float*)d_out;
    float* lossp = out0 + (size_t)N_ * D_;

    emb_prep<<<K_ / 4, 256, 0, stream>>>(emb, embf8, esqh, lossp);
    vq_main<<<N_ / BM, 256, 0, stream>>>(z, embf8, esqh, out0, lossp);
}